// Round 6
// baseline (148.736 us; speedup 1.0000x reference)
//
#include <hip/hip_runtime.h>
#include <hip/hip_bf16.h>

typedef __attribute__((ext_vector_type(8))) short short8;
typedef __attribute__((ext_vector_type(4))) float f32x4;

#define LL 2048
#define DD 128
#define NH 32                      // B*H heads
#define NCHUNK 32                  // m-chunks per head, 64 rows each
#define SCALE 0.08838834764831845f // 1/sqrt(128)

__device__ __forceinline__ unsigned short f2bf(float f) {
  unsigned int u = __float_as_uint(f);
  u = u + 0x7FFFu + ((u >> 16) & 1u);  // RNE; inputs finite
  return (unsigned short)(u >> 16);
}
__device__ __forceinline__ unsigned int pk2(float a, float b) {
  return (unsigned int)f2bf(a) | ((unsigned int)f2bf(b) << 16);
}
__device__ __forceinline__ float fc(const float4& v, int c) {
  return ((const float*)&v)[c];
}

// ---------------------------------------------------------------------------
// Kernel 1: per-chunk partial W_p[d2][d1] = sum_{m in 64-row chunk} V*K
// grid = 32 heads * 32 chunks = 1024 blocks, block = 256 (4 waves).
// LDS 36KB -> 4 blocks/CU: independent blocks stagger load/compute phases.
// Epilogue: shfl lane-pair pack -> bf16 u32 stores (P = 32 MB total).
// ---------------------------------------------------------------------------
template <bool PARTIAL>
__global__ __launch_bounds__(256, 4) void ktv_kernel(const float* __restrict__ Kg,
                                                     const float* __restrict__ Vg,
                                                     void* __restrict__ Pout) {
  const int bh = blockIdx.x >> 5;
  const int chunk = blockIdx.x & 31;
  const int t = threadIdx.x;

  __shared__ unsigned short Kt[128][72];  // [d1][m(64)+pad], 144B rows
  __shared__ unsigned short Vt[128][72];  // [d2][m]

  const int wave = t >> 6;
  const int lane = t & 63;
  const int lr = lane & 15;
  const int kg = lane >> 4;

  const int dq = t >> 3;  // 0..31 d-quad
  const int rp = t & 7;   // row-pair selector
  const size_t hb = (size_t)bh * LL * DD;
  const float* kbase = Kg + hb + (size_t)(chunk * 64 + 2 * rp) * DD + dq * 4;
  const float* vbase = Vg + hb + (size_t)(chunk * 64 + 2 * rp) * DD + dq * 4;

  // issue all 16 loads up front (rows 2rp+16i+j, cols dq*4..+4)
  float4 kv[4][2], vv[4][2];
#pragma unroll
  for (int i = 0; i < 4; ++i)
#pragma unroll
    for (int j = 0; j < 2; ++j) {
      kv[i][j] = *(const float4*)(kbase + (size_t)(16 * i + j) * DD);
      vv[i][j] = *(const float4*)(vbase + (size_t)(16 * i + j) * DD);
    }

  // transpose-write
#pragma unroll
  for (int i = 0; i < 4; ++i)
#pragma unroll
    for (int c = 0; c < 4; ++c) {
      *(unsigned int*)&Kt[dq * 4 + c][16 * i + 2 * rp] =
          pk2(fc(kv[i][0], c), fc(kv[i][1], c));
      *(unsigned int*)&Vt[dq * 4 + c][16 * i + 2 * rp] =
          pk2(fc(vv[i][0], c), fc(vv[i][1], c));
    }
  __syncthreads();

  // wave w: d2 rows [w*32, w*32+32), all 128 d1 cols; K-extent 64 = 2 k-tiles
  f32x4 acc[2][8];
#pragma unroll
  for (int a = 0; a < 2; ++a)
#pragma unroll
    for (int b = 0; b < 8; ++b) acc[a][b] = (f32x4)(0.0f);

#pragma unroll
  for (int kt = 0; kt < 2; ++kt) {
    short8 a0 = *(const short8*)&Vt[wave * 32 + lr][kt * 32 + kg * 8];
    short8 a1 = *(const short8*)&Vt[wave * 32 + 16 + lr][kt * 32 + kg * 8];
#pragma unroll
    for (int tc = 0; tc < 8; ++tc) {
      short8 b = *(const short8*)&Kt[tc * 16 + lr][kt * 32 + kg * 8];
      acc[0][tc] = __builtin_amdgcn_mfma_f32_16x16x32_bf16(a0, b, acc[0][tc], 0, 0, 0);
      acc[1][tc] = __builtin_amdgcn_mfma_f32_16x16x32_bf16(a1, b, acc[1][tc], 0, 0, 0);
    }
  }

  if (PARTIAL) {
    // pack col-pairs across lane pairs, store bf16 u32
    unsigned int* Pu = (unsigned int*)Pout + (size_t)blockIdx.x * 8192;
    const bool ev = (lane & 1) == 0;
#pragma unroll
    for (int tr = 0; tr < 2; ++tr)
#pragma unroll
      for (int tc = 0; tc < 8; ++tc) {
        float m0 = acc[tr][tc][0], m1 = acc[tr][tc][1];
        float m2 = acc[tr][tc][2], m3 = acc[tr][tc][3];
        float o0 = __shfl_xor(m0, 1);
        float o1 = __shfl_xor(m1, 1);
        float o2 = __shfl_xor(m2, 1);
        float o3 = __shfl_xor(m3, 1);
        unsigned int ua = ev ? pk2(m0, o0) : pk2(o2, m2);
        unsigned int ub = ev ? pk2(m1, o1) : pk2(o3, m3);
        int row0 = wave * 32 + tr * 16 + kg * 4 + (ev ? 0 : 2);
        int cp = tc * 8 + (lr >> 1);
        Pu[row0 * 64 + cp] = ua;
        Pu[(row0 + 1) * 64 + cp] = ub;
      }
  } else {
    float* Wh = (float*)Pout + (size_t)bh * DD * DD;
#pragma unroll
    for (int tr = 0; tr < 2; ++tr)
#pragma unroll
      for (int tc = 0; tc < 8; ++tc)
#pragma unroll
        for (int r = 0; r < 4; ++r) {
          int i = wave * 32 + tr * 16 + kg * 4 + r;
          int j = tc * 16 + lr;
          __hip_atomic_fetch_add(&Wh[i * DD + j], acc[tr][tc][r],
                                 __ATOMIC_RELAXED, __HIP_MEMORY_SCOPE_AGENT);
        }
  }
}

// ---------------------------------------------------------------------------
// Reduce: Wu[bh] (bf16 u32-pairs, pre-scaled) = SCALE * sum_{c<32} P[bh*32+c].
// 262144 u32 tasks; grid 1024 x 256, coalesced.
// ---------------------------------------------------------------------------
__global__ __launch_bounds__(256) void reduce_kernel(const unsigned int* __restrict__ Pu,
                                                     unsigned int* __restrict__ Wu) {
  const int task = blockIdx.x * 256 + threadIdx.x;  // bh*8192 + i
  const int bh = task >> 13;
  const int i = task & 8191;
  const unsigned int* p = Pu + ((size_t)bh * NCHUNK) * 8192 + i;
  float sx = 0.f, sy = 0.f;
#pragma unroll
  for (int c = 0; c < NCHUNK; ++c) {
    unsigned int u = p[(size_t)c * 8192];
    sx += __uint_as_float(u << 16);
    sy += __uint_as_float(u & 0xffff0000u);
  }
  Wu[task] = pk2(sx * SCALE, sy * SCALE);
}

// fallback: fp32 W -> bf16 (pre-scaled)
__global__ __launch_bounds__(256) void cvt_kernel(const float* __restrict__ Wf,
                                                  unsigned short* __restrict__ Wb) {
#pragma unroll
  for (int j = 0; j < 4; ++j) {
    int o = blockIdx.x * 1024 + j * 256 + threadIdx.x;
    Wb[o] = f2bf(Wf[o] * SCALE);
  }
}

// ---------------------------------------------------------------------------
// Kernel 2: O[bh][l][d2] = sum_d1 Q[bh][l][d1] * Wb[bh][d2][d1]  (Wb pre-scaled)
// grid = 32 heads * 32 row-blocks (64 rows) = 1024 blocks, block = 256.
// LDS 34.8KB -> 4 blocks/CU. Epilogue: shfl pack -> float2 stores.
// ---------------------------------------------------------------------------
__global__ __launch_bounds__(256, 4) void qw_kernel(const float* __restrict__ Qg,
                                                    const unsigned short* __restrict__ Wb,
                                                    float* __restrict__ Og) {
  const int bh = blockIdx.x >> 5;
  const int rblk = blockIdx.x & 31;
  const int t = threadIdx.x;
  const int wave = t >> 6;
  const int lane = t & 63;
  const int lr = lane & 15;
  const int kg = lane >> 4;

  __shared__ unsigned short Ws[128][136];  // [d2][d1] bf16, pad 8

  // 1) issue all Q loads (8 float4/thread)
  const float* Qb = Qg + ((size_t)bh * LL + rblk * 64 + wave * 16 + lr) * DD;
  float4 q[4][2];
#pragma unroll
  for (int ks = 0; ks < 4; ++ks)
#pragma unroll
    for (int j = 0; j < 2; ++j)
      q[ks][j] = *(const float4*)(Qb + ks * 32 + kg * 8 + j * 4);

  // 2) stage W (32KB = 8 uint4/thread)
  const uint4* Wg = (const uint4*)(Wb + (size_t)bh * (DD * DD));
  uint4 wld[8];
#pragma unroll
  for (int it = 0; it < 8; ++it) wld[it] = Wg[t + it * 256];
#pragma unroll
  for (int it = 0; it < 8; ++it) {
    int g = t + it * 256;  // uint4 index; 16 per 128-short row
    int row = g >> 4;
    int c8 = (g & 15) * 8;
    *(uint4*)&Ws[row][c8] = wld[it];
  }

  // 3) convert q to bf16 while staging lands
  short8 abf[4];
#pragma unroll
  for (int ks = 0; ks < 4; ++ks)
#pragma unroll
    for (int j = 0; j < 2; ++j) {
      abf[ks][j * 4 + 0] = (short)f2bf(q[ks][j].x);
      abf[ks][j * 4 + 1] = (short)f2bf(q[ks][j].y);
      abf[ks][j * 4 + 2] = (short)f2bf(q[ks][j].z);
      abf[ks][j * 4 + 3] = (short)f2bf(q[ks][j].w);
    }
  __syncthreads();

  f32x4 acc[8];
#pragma unroll
  for (int b = 0; b < 8; ++b) acc[b] = (f32x4)(0.0f);

#pragma unroll
  for (int ks = 0; ks < 4; ++ks) {
#pragma unroll
    for (int tc = 0; tc < 8; ++tc) {
      short8 bfr = *(const short8*)&Ws[tc * 16 + lr][ks * 32 + kg * 8];
      acc[tc] = __builtin_amdgcn_mfma_f32_16x16x32_bf16(abf[ks], bfr, acc[tc], 0, 0, 0);
    }
  }

  // epilogue: pack col-pairs across lane pairs -> float2 stores
  float* Ob = Og + ((size_t)bh * LL + rblk * 64 + wave * 16) * DD;
  const bool ev = (lane & 1) == 0;
#pragma unroll
  for (int tc = 0; tc < 8; ++tc) {
    float m0 = acc[tc][0], m1 = acc[tc][1], m2 = acc[tc][2], m3 = acc[tc][3];
    float o0 = __shfl_xor(m0, 1);
    float o1 = __shfl_xor(m1, 1);
    float o2 = __shfl_xor(m2, 1);
    float o3 = __shfl_xor(m3, 1);
    float2 va, vb;
    va.x = ev ? m0 : o2;  va.y = ev ? o0 : m2;
    vb.x = ev ? m1 : o3;  vb.y = ev ? o1 : m3;
    int row0 = kg * 4 + (ev ? 0 : 2);
    int cp = tc * 16 + (lr & ~1);
    *(float2*)&Ob[(size_t)row0 * DD + cp] = va;
    *(float2*)&Ob[(size_t)(row0 + 1) * DD + cp] = vb;
  }
}

extern "C" void kernel_launch(void* const* d_in, const int* in_sizes, int n_in,
                              void* d_out, int out_size, void* d_ws, size_t ws_size,
                              hipStream_t stream) {
  const float* Q = (const float*)d_in[0];
  const float* K = (const float*)d_in[1];
  const float* V = (const float*)d_in[2];
  float* O = (float*)d_out;

  const size_t P_BYTES = (size_t)1024 * 8192 * 4;                        // 32 MB bf16 partials
  const size_t W_BYTES = (size_t)NH * DD * DD * sizeof(unsigned short);  // 1 MB bf16

  if (ws_size >= P_BYTES + W_BYTES) {
    unsigned int* Pu = (unsigned int*)d_ws;
    unsigned short* Wb = (unsigned short*)((char*)d_ws + P_BYTES);
    ktv_kernel<true><<<dim3(1024), dim3(256), 0, stream>>>(K, V, (void*)Pu);
    reduce_kernel<<<dim3(1024), dim3(256), 0, stream>>>(Pu, (unsigned int*)Wb);
    qw_kernel<<<dim3(1024), dim3(256), 0, stream>>>(Q, Wb, O);
  } else {
    // fallback: HW fp32 atomics into 2MB W, then convert+scale to bf16
    float* Wf = (float*)d_ws;
    unsigned short* Wb = (unsigned short*)((char*)d_ws + (size_t)NH * DD * DD * 4);
    hipMemsetAsync(d_ws, 0, (size_t)NH * DD * DD * sizeof(float), stream);
    ktv_kernel<false><<<dim3(1024), dim3(256), 0, stream>>>(K, V, (void*)Wf);
    cvt_kernel<<<dim3(512), dim3(256), 0, stream>>>(Wf, Wb);
    qw_kernel<<<dim3(1024), dim3(256), 0, stream>>>(Q, Wb, O);
  }
}

// Round 8
// 147.802 us; speedup vs baseline: 1.0063x; 1.0063x over previous
//
#include <hip/hip_runtime.h>
#include <hip/hip_bf16.h>

typedef __attribute__((ext_vector_type(8))) short short8;
typedef __attribute__((ext_vector_type(4))) float f32x4;

#define LL 2048
#define DD 128
#define NH 32                      // B*H heads
#define SCALE 0.08838834764831845f // 1/sqrt(128)

__device__ __forceinline__ unsigned short f2bf(float f) {
  unsigned int u = __float_as_uint(f);
  u = u + 0x7FFFu + ((u >> 16) & 1u);  // RNE; inputs finite
  return (unsigned short)(u >> 16);
}
__device__ __forceinline__ unsigned int pk2(float a, float b) {
  return (unsigned int)f2bf(a) | ((unsigned int)f2bf(b) << 16);
}
__device__ __forceinline__ float fc(const float4& v, int c) {
  return ((const float*)&v)[c];
}

// ---------------------------------------------------------------------------
// Kernel 1: per-chunk partial W_p[d2][d1] = sum_{m in chunk} V[m][d2]*K[m][d1]
// grid = 32 heads * 16 chunks (128 m-rows each), block = 512 (8 waves).
// 2 blocks/CU -> 16 waves/CU. Register double-buffer across the 4 m-tiles.
// Wave w computes W rows [w*16, w*16+16) x all 128 cols (8 MFMA frags).
// ---------------------------------------------------------------------------
template <bool PARTIAL>
__global__ __launch_bounds__(512, 4) void ktv_kernel(const float* __restrict__ Kg,
                                                     const float* __restrict__ Vg,
                                                     float* __restrict__ P) {
  const int bh = blockIdx.x >> 4;
  const int chunk = blockIdx.x & 15;
  const int t = threadIdx.x;

  __shared__ unsigned short Kt[128][40];  // [d][m-tile(32)], 80B rows
  __shared__ unsigned short Vt[128][40];

  const int wave = t >> 6;
  const int lane = t & 63;
  const int lr = lane & 15;
  const int kg = lane >> 4;

  f32x4 acc[8];
#pragma unroll
  for (int b = 0; b < 8; ++b) acc[b] = (f32x4)(0.0f);

  const int dq = t >> 4;        // 0..31 : d-quad
  const int mr = (t & 15) << 1; // 0..30 : m-row base (2 rows/thread)
  const size_t hb = (size_t)bh * LL * DD;
  const float* kbase = Kg + hb + (size_t)(chunk * 128 + mr) * DD + dq * 4;
  const float* vbase = Vg + hb + (size_t)(chunk * 128 + mr) * DD + dq * 4;

  float4 k0a, k1a, v0a, v1a, k0b, k1b, v0b, v1b;
  k0a = *(const float4*)(kbase);
  k1a = *(const float4*)(kbase + DD);
  v0a = *(const float4*)(vbase);
  v1a = *(const float4*)(vbase + DD);

#pragma unroll
  for (int tile = 0; tile < 4; ++tile) {
    if (tile < 3) {  // prefetch next 32-row tile into regs
      const float* kp = kbase + (size_t)(tile + 1) * 32 * DD;
      const float* vp = vbase + (size_t)(tile + 1) * 32 * DD;
      k0b = *(const float4*)(kp);
      k1b = *(const float4*)(kp + DD);
      v0b = *(const float4*)(vp);
      v1b = *(const float4*)(vp + DD);
    }
    if (tile) __syncthreads();  // prior tile's frag reads complete

#pragma unroll
    for (int c = 0; c < 4; ++c) {
      *(unsigned int*)&Kt[dq * 4 + c][mr] = pk2(fc(k0a, c), fc(k1a, c));
      *(unsigned int*)&Vt[dq * 4 + c][mr] = pk2(fc(v0a, c), fc(v1a, c));
    }
    __syncthreads();

    short8 a0 = *(const short8*)&Vt[wave * 16 + lr][kg * 8];
#pragma unroll
    for (int tc = 0; tc < 8; ++tc) {
      short8 b = *(const short8*)&Kt[tc * 16 + lr][kg * 8];
      acc[tc] = __builtin_amdgcn_mfma_f32_16x16x32_bf16(a0, b, acc[tc], 0, 0, 0);
    }
    if (tile < 3) {
      k0a = k0b; k1a = k1b; v0a = v0b; v1a = v1b;
    }
  }

  if (PARTIAL) {
    float* Pp = P + (size_t)blockIdx.x * (DD * DD);
#pragma unroll
    for (int tc = 0; tc < 8; ++tc)
#pragma unroll
      for (int r = 0; r < 4; ++r) {
        int i = wave * 16 + kg * 4 + r;
        int j = tc * 16 + lr;
        Pp[i * DD + j] = acc[tc][r];
      }
  } else {
    float* Wh = P + (size_t)bh * DD * DD;
#pragma unroll
    for (int tc = 0; tc < 8; ++tc)
#pragma unroll
      for (int r = 0; r < 4; ++r) {
        int i = wave * 16 + kg * 4 + r;
        int j = tc * 16 + lr;
        __hip_atomic_fetch_add(&Wh[i * DD + j], acc[tc][r],
                               __ATOMIC_RELAXED, __HIP_MEMORY_SCOPE_AGENT);
      }
  }
}

// ---------------------------------------------------------------------------
// Reduce: Wb[bh] (bf16, pre-scaled) = SCALE * sum_{c=0..15} P[bh*16+c].
// 131072 tasks of float4; grid 512 x 256, 1 task/thread, coalesced.
// ---------------------------------------------------------------------------
__global__ __launch_bounds__(256) void reduce_kernel(const float* __restrict__ P,
                                                     unsigned short* __restrict__ Wb) {
  const int task = blockIdx.x * 256 + threadIdx.x;  // bh*4096 + i4
  const int bh = task >> 12;
  const int i4 = task & 4095;
  const float4* p = (const float4*)P + (((size_t)bh << 4) << 12) + i4;
  float4 s = make_float4(0.f, 0.f, 0.f, 0.f);
#pragma unroll
  for (int c = 0; c < 16; ++c) {
    float4 x = p[(size_t)c << 12];
    s.x += x.x; s.y += x.y; s.z += x.z; s.w += x.w;
  }
  uint2 o;
  o.x = pk2(s.x * SCALE, s.y * SCALE);
  o.y = pk2(s.z * SCALE, s.w * SCALE);
  ((uint2*)Wb)[task] = o;
}

// fallback: fp32 W -> bf16 (pre-scaled)
__global__ __launch_bounds__(256) void cvt_kernel(const float* __restrict__ Wf,
                                                  unsigned short* __restrict__ Wb) {
#pragma unroll
  for (int j = 0; j < 4; ++j) {
    int o = blockIdx.x * 1024 + j * 256 + threadIdx.x;
    Wb[o] = f2bf(Wf[o] * SCALE);
  }
}

// ---------------------------------------------------------------------------
// Kernel 2: O[bh][l][d2] = sum_d1 Q[bh][l][d1] * Wb[bh][d2][d1]  (Wb pre-scaled)
// grid = 32 heads * 16 row-blocks (128 rows), block = 512 (8 waves x 16 rows).
// Q issued before W staging; q->bf16 converted while W staging lands.
// ---------------------------------------------------------------------------
__global__ __launch_bounds__(512, 4) void qw_kernel(const float* __restrict__ Qg,
                                                    const unsigned short* __restrict__ Wb,
                                                    float* __restrict__ Og) {
  const int bh = blockIdx.x >> 4;
  const int rblk = blockIdx.x & 15;
  const int t = threadIdx.x;
  const int wave = t >> 6;
  const int lane = t & 63;
  const int lr = lane & 15;
  const int kg = lane >> 4;

  __shared__ unsigned short Ws[128][136];  // [d2][d1] bf16, pad 8

  // 1) issue all Q loads (8 float4/thread; lane's 32B contiguous per ks)
  const float* Qb = Qg + ((size_t)bh * LL + rblk * 128 + wave * 16 + lr) * DD;
  float4 q[4][2];
#pragma unroll
  for (int ks = 0; ks < 4; ++ks)
#pragma unroll
    for (int j = 0; j < 2; ++j)
      q[ks][j] = *(const float4*)(Qb + ks * 32 + kg * 8 + j * 4);

  // 2) stage W (bf16, 32KB = 4 uint4/thread)
  const uint4* Wg = (const uint4*)(Wb + (size_t)bh * (DD * DD));
  uint4 wld[4];
#pragma unroll
  for (int it = 0; it < 4; ++it) wld[it] = Wg[t + it * 512];
#pragma unroll
  for (int it = 0; it < 4; ++it) {
    int g = t + it * 512;  // uint4 index; 16 per 128-short row
    int row = g >> 4;
    int c8 = (g & 15) * 8;
    *(uint4*)&Ws[row][c8] = wld[it];
  }

  // 3) convert q to bf16 fragments while W staging lands
  short8 abf[4];
#pragma unroll
  for (int ks = 0; ks < 4; ++ks)
#pragma unroll
    for (int j = 0; j < 2; ++j) {
      abf[ks][j * 4 + 0] = (short)f2bf(q[ks][j].x);
      abf[ks][j * 4 + 1] = (short)f2bf(q[ks][j].y);
      abf[ks][j * 4 + 2] = (short)f2bf(q[ks][j].z);
      abf[ks][j * 4 + 3] = (short)f2bf(q[ks][j].w);
    }
  __syncthreads();

  f32x4 acc[8];
#pragma unroll
  for (int b = 0; b < 8; ++b) acc[b] = (f32x4)(0.0f);

#pragma unroll
  for (int ks = 0; ks < 4; ++ks) {
#pragma unroll
    for (int tc = 0; tc < 8; ++tc) {
      short8 bfr = *(const short8*)&Ws[tc * 16 + lr][ks * 32 + kg * 8];
      acc[tc] = __builtin_amdgcn_mfma_f32_16x16x32_bf16(abf[ks], bfr, acc[tc], 0, 0, 0);
    }
  }

  float* Ob = Og + ((size_t)bh * LL + rblk * 128 + wave * 16) * DD;
#pragma unroll
  for (int tc = 0; tc < 8; ++tc)
#pragma unroll
    for (int r = 0; r < 4; ++r)
      Ob[(kg * 4 + r) * DD + tc * 16 + lr] = acc[tc][r];
}

extern "C" void kernel_launch(void* const* d_in, const int* in_sizes, int n_in,
                              void* d_out, int out_size, void* d_ws, size_t ws_size,
                              hipStream_t stream) {
  const float* Q = (const float*)d_in[0];
  const float* K = (const float*)d_in[1];
  const float* V = (const float*)d_in[2];
  float* O = (float*)d_out;

  const size_t P_BYTES = (size_t)512 * DD * DD * sizeof(float);             // 32 MB
  const size_t W_BYTES = (size_t)NH * DD * DD * sizeof(unsigned short);     // 1 MB

  if (ws_size >= P_BYTES + W_BYTES) {
    float* P = (float*)d_ws;
    unsigned short* Wb = (unsigned short*)((char*)d_ws + P_BYTES);
    ktv_kernel<true><<<dim3(512), dim3(512), 0, stream>>>(K, V, P);
    reduce_kernel<<<dim3(512), dim3(256), 0, stream>>>(P, Wb);
    qw_kernel<<<dim3(512), dim3(512), 0, stream>>>(Q, Wb, O);
  } else {
    // fallback: HW fp32 atomics into 2MB W, then convert+scale to bf16
    float* Wf = (float*)d_ws;
    unsigned short* Wb = (unsigned short*)((char*)d_ws + (size_t)NH * DD * DD * 4);
    hipMemsetAsync(d_ws, 0, (size_t)NH * DD * DD * sizeof(float), stream);
    ktv_kernel<false><<<dim3(512), dim3(512), 0, stream>>>(K, V, Wf);
    cvt_kernel<<<dim3(512), dim3(256), 0, stream>>>(Wf, Wb);
    qw_kernel<<<dim3(512), dim3(512), 0, stream>>>(Q, Wb, O);
  }
}